// Round 4
// baseline (288.230 us; speedup 1.0000x reference)
//
#include <hip/hip_runtime.h>

// MaskedGNN on MI355X — round 4: 2-launch design.
// prep_kernel packs/folds weights; mega_kernel = one block per batch element
// runs encoder -> 3 GATv2 layers -> pool -> decoder entirely in 64 KB LDS.
// H=128, N=64, B=128, L=3, F=7, E=64.
//
// MFMA fragments (16x16x32 bf16):
//   A-frag: lane holds A[m=lane&15][k=(lane>>4)*8+j]
//   B-frag: lane holds B[k=(lane>>4)*8+j][n=lane&15]
//   C/D:    col=lane&15, row=(lane>>4)*4+reg

constexpr float EPS = 1e-5f;
constexpr float NEGI = -1e9f;

typedef __bf16 bf16x8 __attribute__((ext_vector_type(8)));
typedef float floatx4 __attribute__((ext_vector_type(4)));
typedef _Float16 h2 __attribute__((ext_vector_type(2)));

union U32H2 { unsigned int u; h2 h; };

__device__ __forceinline__ bf16x8 cvt8(const float* p) {
  float t[8];
  *(float4*)t = *(const float4*)p;
  *(float4*)(t + 4) = *(const float4*)(p + 4);
  bf16x8 r;
#pragma unroll
  for (int j = 0; j < 8; ++j) r[j] = (__bf16)t[j];
  return r;
}

__device__ __forceinline__ float fdot2h(h2 a, h2 b, float c) {
#if __has_builtin(__builtin_amdgcn_fdot2)
  return __builtin_amdgcn_fdot2(a, b, c, false);
#else
  return c + (float)a[0] * (float)b[0] + (float)a[1] * (float)b[1];
#endif
}

// ---------------------------------------------------------------------------
// prep: blocks 0..47 fold Wqe/Wke -> wcatpk (nt 8..23); 48..55 pack plain
// weights; 56 bcat = {bv, bq@We1a, bk@We1b+be1}.  (verified in round 3)
__global__ __launch_bounds__(256) void prep_kernel(
    const float* __restrict__ Wq, const float* __restrict__ bq,
    const float* __restrict__ Wk, const float* __restrict__ bk,
    const float* __restrict__ bv, const float* __restrict__ We1,
    const float* __restrict__ be1,
    const float* __restrict__ eW1, const float* __restrict__ eW2,
    const float* __restrict__ Wv, const float* __restrict__ Wo,
    __bf16* __restrict__ w1pk, __bf16* __restrict__ w2pk,
    __bf16* __restrict__ wcatpk, __bf16* __restrict__ wopk,
    float* __restrict__ bcat) {
  int tid = threadIdx.x, blk = blockIdx.x;
  if (blk < 48) {
    __shared__ float sB[128 * 16];
    __shared__ float sF[128 * 17];
    int jb = blk >> 3, cc = blk & 7;
    int l = jb >> 1, w = jb & 1;
    const float* A = (w ? Wk : Wq) + l * 16384;
    const float* Bm = We1 + l * 32768 + w * 16384;
    int c0 = cc * 16;
    for (int idx = tid; idx < 2048; idx += 256) {
      int m = idx >> 4, c = idx & 15;
      sB[idx] = Bm[m * 128 + c0 + c];
    }
    __syncthreads();
    int r = tid >> 1, c8 = (tid & 1) * 8;
    float acc[8] = {};
    const float4* A4 = (const float4*)(A + r * 128);
#pragma unroll 8
    for (int k4 = 0; k4 < 32; ++k4) {
      float4 a = A4[k4];
      float av[4] = {a.x, a.y, a.z, a.w};
#pragma unroll
      for (int kk = 0; kk < 4; ++kk)
#pragma unroll
        for (int c = 0; c < 8; ++c)
          acc[c] = fmaf(av[kk], sB[(k4 * 4 + kk) * 16 + c8 + c], acc[c]);
    }
    for (int c = 0; c < 8; ++c) sF[r * 17 + c8 + c] = acc[c];
    __syncthreads();
    int kc = tid >> 6, lane = tid & 63;
    int k0 = kc * 32 + (lane >> 4) * 8, n = lane & 15;
    bf16x8 pk;
#pragma unroll
    for (int j = 0; j < 8; ++j) pk[j] = (__bf16)sF[(k0 + j) * 17 + n];
    int ntg = 8 + w * 8 + cc;
    *((bf16x8*)(wcatpk + l * 49152) + (ntg * 4 + kc) * 64 + lane) = pk;
  } else if (blk < 56) {
    int job = blk - 48;
    const float* src;
    __bf16* dst;
    int KCH = 4;
    if (job == 0) { src = eW1; dst = w1pk; KCH = 2; }
    else if (job == 1) { src = eW2; dst = w2pk; }
    else if (job < 5) { int l = job - 2; src = Wv + l * 16384; dst = wcatpk + l * 49152; }
    else { int l = job - 5; src = Wo + l * 16384; dst = wopk + l * 16384; }
    for (int s = tid; s < 8 * KCH * 64; s += 256) {
      int lane = s & 63, q = s >> 6;
      int kc = q % KCH, nt = q / KCH;
      int k0 = kc * 32 + (lane >> 4) * 8, n = nt * 16 + (lane & 15);
      bf16x8 pk;
#pragma unroll
      for (int j = 0; j < 8; ++j) pk[j] = (__bf16)src[(k0 + j) * 128 + n];
      *((bf16x8*)dst + (nt * KCH + kc) * 64 + lane) = pk;
    }
  } else {
    for (int idx = tid; idx < 3 * 384; idx += 256) {
      int l = idx / 384, c = idx % 384;
      float val;
      if (c < 128) {
        val = bv[l * 128 + c];
      } else if (c < 256) {
        int cc = c - 128;
        float s = 0.f;
        for (int k = 0; k < 128; ++k) s += bq[l * 128 + k] * We1[l * 32768 + k * 128 + cc];
        val = s;
      } else {
        int cc = c - 256;
        float s = be1[l * 128 + cc];
        for (int k = 0; k < 128; ++k) s += bk[l * 128 + k] * We1[l * 32768 + 16384 + k * 128 + cc];
        val = s;
      }
      bcat[l * 384 + c] = val;
    }
  }
}

// ---------------------------------------------------------------------------
// LN over SF (f32 64x128, swizzled (c+4*row)&127) with 512 threads.
// Each thread owns row r=tid>>3, cols c8=(tid&7)*16..+15. Optional mask,
// pack->SX (bf16 packed-A), pool partials -> SP.
__device__ __forceinline__ void ln512(unsigned char* SM, const float* __restrict__ g,
                                      const float* __restrict__ be, float mreg,
                                      bool domask, bool dopack, bool dopool, int tid) {
  float* SF = (float*)(SM + 16384);
  int r = tid >> 3, c0 = tid & 7;
  const float* base = SF + r * 128;
  float s = 0.f, q = 0.f;
#pragma unroll
  for (int k = 0; k < 16; ++k) {
    float v = base[(c0 + 8 * k + 4 * r) & 127];
    s += v; q += v * v;
  }
  s += __shfl_xor(s, 1); s += __shfl_xor(s, 2); s += __shfl_xor(s, 4);
  q += __shfl_xor(q, 1); q += __shfl_xor(q, 2); q += __shfl_xor(q, 4);
  float m = s * (1.f / 128.f);
  float rs = rsqrtf(fmaxf(q * (1.f / 128.f) - m * m, 0.f) + EPS);
  float mk = domask ? __shfl(mreg, r) : 1.f;
  int c8 = c0 * 16;
  float vals[16];
#pragma unroll
  for (int tq = 0; tq < 4; ++tq)
    *(float4*)(vals + tq * 4) = *(const float4*)(base + ((c8 + 4 * r + 4 * tq) & 127));
#pragma unroll
  for (int k2 = 0; k2 < 16; ++k2) {
    int c = c8 + k2;
    vals[k2] = fmaxf((vals[k2] - m) * rs * g[c] + be[c], 0.f) * mk;
  }
  if (dopack) {
#pragma unroll
    for (int hh = 0; hh < 2; ++hh) {
      int ch = c8 + hh * 8;
      bf16x8 pk;
#pragma unroll
      for (int j2 = 0; j2 < 8; ++j2) pk[j2] = (__bf16)vals[hh * 8 + j2];
      ((bf16x8*)SM)[((r >> 4) * 4 + (ch >> 5)) * 64 + ((ch >> 3) & 3) * 16 + (r & 15)] = pk;
    }
  }
  if (dopool) {
    float* SP = (float*)(SM + 49152);
#pragma unroll
    for (int k2 = 0; k2 < 16; ++k2) {
      float v = vals[k2];
      v += __shfl_xor(v, 8); v += __shfl_xor(v, 16); v += __shfl_xor(v, 32);
      vals[k2] = v;
    }
    int lane = tid & 63, wvv = tid >> 6;
    if ((lane >> 3) == 0) {
#pragma unroll
      for (int tq = 0; tq < 4; ++tq)
        *(float4*)(SP + wvv * 128 + c8 + tq * 4) = *(float4*)(vals + tq * 4);
    }
  }
}

// ---------------------------------------------------------------------------
__global__ __launch_bounds__(512, 2) void mega_kernel(
    const float* __restrict__ emb, const float* __restrict__ mask,
    const float* __restrict__ bfeat,
    const float* __restrict__ eb1, const float* __restrict__ eg1, const float* __restrict__ eB1,
    const float* __restrict__ eb2, const float* __restrict__ eg2, const float* __restrict__ eB2,
    const __bf16* __restrict__ w1pk, const __bf16* __restrict__ w2pk,
    const __bf16* __restrict__ wcatpk, const float* __restrict__ bcat,
    const float* __restrict__ We2, const float* __restrict__ be2,
    const __bf16* __restrict__ wopk, const float* __restrict__ bo,
    const float* __restrict__ og, const float* __restrict__ oB,
    const float* __restrict__ dW1, const float* __restrict__ db1,
    const float* __restrict__ dg1, const float* __restrict__ dB1,
    const float* __restrict__ dW2, const float* __restrict__ db2,
    const float* __restrict__ dg2, const float* __restrict__ dB2,
    const float* __restrict__ dW3, const float* __restrict__ db3,
    float* __restrict__ out) {
  __shared__ __align__(16) unsigned char SM[65536];
  __bf16* SX = (__bf16*)SM;                          // 16 KB: packed x / attn
  unsigned int* LQ = (unsigned int*)(SM + 16384);    // f16 hq [hp][(i+hp)&63]
  unsigned int* LK = (unsigned int*)(SM + 32768);    // f16 hk [hp][(j+hp)&63]
  float* SF = (float*)(SM + 16384);                  // 32 KB f32 scratch (aliases LQ+LK)
  __bf16* SV = (__bf16*)(SM + 49152);                // 16 KB packed-B v
  float* SP = (float*)(SM + 49152);                  // pool/dec partials (aliases SV)
  float* sd  = (float*)(SM + 53248);                 // s_d[135]
  float* sz  = (float*)(SM + 53824);                 // s_z[128]
  float* sz2 = (float*)(SM + 54336);                 // s_z2[128]
  float* red = (float*)(SM + 54848);                 // red[16]

  int tid = threadIdx.x;
  int lane = tid & 63, wv = tid >> 6;
  int quad = lane >> 4, cl = lane & 15;
  int b = blockIdx.x;
  const float* embb = emb + b * 4096;
  float mreg = mask[b * 64 + lane];

  // ================= E1 (K=64, N=128): wave wv owns ntile wv =================
  {
    bf16x8 a[4][2];
#pragma unroll
    for (int mt = 0; mt < 4; ++mt)
#pragma unroll
      for (int kc = 0; kc < 2; ++kc)
        a[mt][kc] = cvt8(embb + (mt * 16 + cl) * 64 + kc * 32 + quad * 8);
    floatx4 acc[4];
#pragma unroll
    for (int mt = 0; mt < 4; ++mt) acc[mt] = 0;
#pragma unroll
    for (int kc = 0; kc < 2; ++kc) {
      bf16x8 bw = *((const bf16x8*)w1pk + (wv * 2 + kc) * 64 + lane);
#pragma unroll
      for (int mt = 0; mt < 4; ++mt)
        acc[mt] = __builtin_amdgcn_mfma_f32_16x16x32_bf16(a[mt][kc], bw, acc[mt], 0, 0, 0);
    }
    int col = wv * 16 + cl;
    float bb = eb1[col];
#pragma unroll
    for (int mt = 0; mt < 4; ++mt)
#pragma unroll
      for (int r = 0; r < 4; ++r) {
        int row = mt * 16 + quad * 4 + r;
        SF[row * 128 + ((col + 4 * row) & 127)] = acc[mt][r] + bb;
      }
  }
  __syncthreads();
  ln512(SM, eg1, eB1, mreg, false, true, false, tid);
  __syncthreads();

  // ================= E2 (K=128, N=128) =================
  {
    bf16x8 a[4][4];
#pragma unroll
    for (int mt = 0; mt < 4; ++mt)
#pragma unroll
      for (int kc = 0; kc < 4; ++kc)
        a[mt][kc] = *((const bf16x8*)SX + (mt * 4 + kc) * 64 + lane);
    floatx4 acc[4];
#pragma unroll
    for (int mt = 0; mt < 4; ++mt) acc[mt] = 0;
#pragma unroll
    for (int kc = 0; kc < 4; ++kc) {
      bf16x8 bw = *((const bf16x8*)w2pk + (wv * 4 + kc) * 64 + lane);
#pragma unroll
      for (int mt = 0; mt < 4; ++mt)
        acc[mt] = __builtin_amdgcn_mfma_f32_16x16x32_bf16(a[mt][kc], bw, acc[mt], 0, 0, 0);
    }
    __syncthreads();   // all SX A-preloads done before ln512 repacks SX below
    int col = wv * 16 + cl;
    float bb = eb2[col];
#pragma unroll
    for (int mt = 0; mt < 4; ++mt)
#pragma unroll
      for (int r = 0; r < 4; ++r) {
        int row = mt * 16 + quad * 4 + r;
        SF[row * 128 + ((col + 4 * row) & 127)] = acc[mt][r] + bb;
      }
  }
  __syncthreads();
  ln512(SM, eg2, eB2, mreg, true, true, false, tid);
  __syncthreads();

  // ================= layers =================
  for (int l = 0; l < 3; ++l) {
    const bf16x8* wc = (const bf16x8*)(wcatpk + l * 49152);
    const bf16x8* wo = (const bf16x8*)(wopk + l * 16384);
    const float* bc = bcat + l * 384;
    const float* we2l = We2 + l * 128;
    float be2v = be2[l];
    const float* bol = bo + l * 128;
    const float* ogl = og + l * 128;
    const float* oBl = oB + l * 128;

    // ---- qkv: wave owns 3 ntiles (of 24), all 4 mtiles ----
    {
      bf16x8 a[4][4];
#pragma unroll
      for (int mt = 0; mt < 4; ++mt)
#pragma unroll
        for (int kc = 0; kc < 4; ++kc)
          a[mt][kc] = *((const bf16x8*)SX + (mt * 4 + kc) * 64 + lane);
      floatx4 acc[3][4];
#pragma unroll
      for (int n = 0; n < 3; ++n)
#pragma unroll
        for (int mt = 0; mt < 4; ++mt) acc[n][mt] = 0;
#pragma unroll
      for (int kc = 0; kc < 4; ++kc)
#pragma unroll
        for (int n = 0; n < 3; ++n) {
          bf16x8 bw = wc[((wv * 3 + n) * 4 + kc) * 64 + lane];
#pragma unroll
          for (int mt = 0; mt < 4; ++mt)
            acc[n][mt] = __builtin_amdgcn_mfma_f32_16x16x32_bf16(a[mt][kc], bw, acc[n][mt], 0, 0, 0);
        }
#pragma unroll
      for (int n = 0; n < 3; ++n) {
        int g = wv * 3 + n;
        if (g < 8) {                       // v -> SV packed-B (bf16)
          float bb = bc[g * 16 + cl];
#pragma unroll
          for (int mt = 0; mt < 4; ++mt)
#pragma unroll
            for (int r = 0; r < 4; ++r) {
              int j = mt * 16 + quad * 4 + r;
              SV[((g * 2 + (j >> 5)) * 64 + ((j >> 3) & 3) * 16 + cl) * 8 + (j & 7)] =
                  (__bf16)(acc[n][mt][r] + bb);
            }
        } else if (g < 16) {               // hq -> LQ (f16, swizzled [hp][(i+hp)&63])
          int h = (g - 8) * 16 + cl;
          float bb = bc[128 + h];
          int hp = h >> 1;
#pragma unroll
          for (int mt = 0; mt < 4; ++mt)
#pragma unroll
            for (int r = 0; r < 4; ++r) {
              int i = mt * 16 + quad * 4 + r;
              *(_Float16*)(SM + 16384 + (hp * 64 + ((i + hp) & 63)) * 4 + (h & 1) * 2) =
                  (_Float16)(acc[n][mt][r] + bb);
            }
        } else {                           // hk -> LK
          int h = (g - 16) * 16 + cl;
          float bb = bc[256 + h];
          int hp = h >> 1;
#pragma unroll
          for (int mt = 0; mt < 4; ++mt)
#pragma unroll
            for (int r = 0; r < 4; ++r) {
              int j = mt * 16 + quad * 4 + r;
              *(_Float16*)(SM + 32768 + (hp * 64 + ((j + hp) & 63)) * 4 + (h & 1) * 2) =
                  (_Float16)(acc[n][mt][r] + bb);
            }
        }
      }
    }
    __syncthreads();

    // ---- scores + softmax: wave owns 8 i-rows, lane = j ----
    {
      int i0 = wv * 8;
      unsigned int hq_u[8];
#pragma unroll
      for (int ii = 0; ii < 8; ++ii)
        hq_u[ii] = LQ[lane * 64 + ((i0 + ii + lane) & 63)];
      U32H2 w2c;
      w2c.h[0] = (_Float16)we2l[2 * lane];
      w2c.h[1] = (_Float16)we2l[2 * lane + 1];
      float acc8[8];
#pragma unroll
      for (int ii = 0; ii < 8; ++ii) acc8[ii] = 0.f;
      h2 hz = {(_Float16)0.0f, (_Float16)0.0f};
#pragma unroll
      for (int hp = 0; hp < 64; ++hp) {
        U32H2 hk; hk.u = LK[hp * 64 + ((lane + hp) & 63)];
        U32H2 w2h; w2h.u = (unsigned int)__shfl((int)w2c.u, hp);
#pragma unroll
        for (int ii = 0; ii < 8; ++ii) {
          U32H2 hq; hq.u = (unsigned int)__shfl((int)hq_u[ii], hp);
          h2 s2 = hq.h + hk.h;
          s2 = __builtin_elementwise_max(s2, hz);
          acc8[ii] = fdot2h(s2, w2h.h, acc8[ii]);
        }
      }
      float mj = mreg;
#pragma unroll
      for (int ii = 0; ii < 8; ++ii) {
        int i = i0 + ii;
        float mi = __shfl(mreg, i);
        float m2 = mi * mj;
        float sc = (m2 > 0.f) ? acc8[ii] + be2v : NEGI;
        float mx = sc;
#pragma unroll
        for (int off = 32; off >= 1; off >>= 1) mx = fmaxf(mx, __shfl_xor(mx, off));
        float p = __expf(sc - mx);
        float sm = p;
#pragma unroll
        for (int off = 32; off >= 1; off >>= 1) sm += __shfl_xor(sm, off);
        ((__bf16*)SM)[i * 72 + lane] = (__bf16)(p / sm * m2);
      }
    }
    __syncthreads();

    // ---- agg = attn @ v: wave owns ntile wv ----
    {
      bf16x8 aat[4][2];
#pragma unroll
      for (int mt = 0; mt < 4; ++mt)
#pragma unroll
        for (int kc = 0; kc < 2; ++kc)
          aat[mt][kc] = *(const bf16x8*)(SM + ((mt * 16 + cl) * 72 + kc * 32 + quad * 8) * 2);
      __syncthreads();   // all attn reads done before repacking SX
      floatx4 acc[4];
#pragma unroll
      for (int mt = 0; mt < 4; ++mt) acc[mt] = 0;
#pragma unroll
      for (int kc = 0; kc < 2; ++kc) {
        bf16x8 bw = ((const bf16x8*)SV)[(wv * 2 + kc) * 64 + lane];
#pragma unroll
        for (int mt = 0; mt < 4; ++mt)
          acc[mt] = __builtin_amdgcn_mfma_f32_16x16x32_bf16(aat[mt][kc], bw, acc[mt], 0, 0, 0);
      }
      int hcol = wv * 16 + cl;
      int kc2 = hcol >> 5, q2 = (hcol >> 3) & 3, jj = hcol & 7;
#pragma unroll
      for (int mt = 0; mt < 4; ++mt)
#pragma unroll
        for (int r = 0; r < 4; ++r) {
          int i = mt * 16 + quad * 4 + r;
          SX[((mt * 4 + kc2) * 64 + q2 * 16 + (i & 15)) * 8 + jj] = (__bf16)acc[mt][r];
        }
    }
    __syncthreads();

    // ---- Wo GEMM: wave owns ntile wv ----
    {
      bf16x8 a[4][4];
#pragma unroll
      for (int mt = 0; mt < 4; ++mt)
#pragma unroll
        for (int kc = 0; kc < 4; ++kc)
          a[mt][kc] = *((const bf16x8*)SX + (mt * 4 + kc) * 64 + lane);
      floatx4 acc[4];
#pragma unroll
      for (int mt = 0; mt < 4; ++mt) acc[mt] = 0;
#pragma unroll
      for (int kc = 0; kc < 4; ++kc) {
        bf16x8 bw = wo[(wv * 4 + kc) * 64 + lane];
#pragma unroll
        for (int mt = 0; mt < 4; ++mt)
          acc[mt] = __builtin_amdgcn_mfma_f32_16x16x32_bf16(a[mt][kc], bw, acc[mt], 0, 0, 0);
      }
      int col = wv * 16 + cl;
      float bb = bol[col];
#pragma unroll
      for (int mt = 0; mt < 4; ++mt)
#pragma unroll
        for (int r = 0; r < 4; ++r) {
          int row = mt * 16 + quad * 4 + r;
          SF[row * 128 + ((col + 4 * row) & 127)] = acc[mt][r] + bb;
        }
    }
    __syncthreads();
    ln512(SM, ogl, oBl, mreg, true, l < 2, l == 2, tid);
    __syncthreads();
  }

  // ================= decoder =================
  float den = mreg;
#pragma unroll
  for (int off = 32; off >= 1; off >>= 1) den += __shfl_xor(den, off);
  den = fmaxf(den, 1.f);

  if (tid < 7) sd[tid] = bfeat[b * 7 + tid];
  if (tid < 128) {
    float s = 0.f;
#pragma unroll
    for (int w = 0; w < 8; ++w) s += SP[w * 128 + tid];
    sd[7 + tid] = s / den;
  }
  __syncthreads();

  int t = tid & 127, g4 = tid >> 7;
  {
    float zp = 0.f;
    for (int k = g4; k < 135; k += 4) zp = fmaf(sd[k], dW1[k * 128 + t], zp);
    SP[g4 * 128 + t] = zp;
  }
  __syncthreads();
  float z = db1[t] + SP[t] + SP[128 + t] + SP[256 + t] + SP[384 + t];
  {
    float s = z, q = z * z;
#pragma unroll
    for (int off = 32; off >= 1; off >>= 1) { s += __shfl_xor(s, off); q += __shfl_xor(q, off); }
    if (lane == 0) { red[wv] = s; red[8 + wv] = q; }
    __syncthreads();
    float S = 0.f, Q = 0.f;
#pragma unroll
    for (int w = 0; w < 8; ++w) { S += red[w]; Q += red[8 + w]; }
    S *= 0.25f; Q *= 0.25f;
    float m = S * (1.f / 128.f);
    float rs = rsqrtf(fmaxf(Q * (1.f / 128.f) - m * m, 0.f) + EPS);
    z = fmaxf((z - m) * rs * dg1[t] + dB1[t], 0.f);
    __syncthreads();
  }
  sz[t] = z;
  __syncthreads();
  {
    float zp = 0.f;
    for (int k = g4; k < 128; k += 4) zp = fmaf(sz[k], dW2[k * 128 + t], zp);
    SP[g4 * 128 + t] = zp;
  }
  __syncthreads();
  float z2 = db2[t] + SP[t] + SP[128 + t] + SP[256 + t] + SP[384 + t];
  {
    float s = z2, q = z2 * z2;
#pragma unroll
    for (int off = 32; off >= 1; off >>= 1) { s += __shfl_xor(s, off); q += __shfl_xor(q, off); }
    if (lane == 0) { red[wv] = s; red[8 + wv] = q; }
    __syncthreads();
    float S = 0.f, Q = 0.f;
#pragma unroll
    for (int w = 0; w < 8; ++w) { S += red[w]; Q += red[8 + w]; }
    S *= 0.25f; Q *= 0.25f;
    float m = S * (1.f / 128.f);
    float rs = rsqrtf(fmaxf(Q * (1.f / 128.f) - m * m, 0.f) + EPS);
    z2 = fmaxf((z2 - m) * rs * dg2[t] + dB2[t], 0.f);
    __syncthreads();
  }
  sz2[t] = z2;
  __syncthreads();
  if (tid < 7) {
    float o = db3[tid];
    for (int k = 0; k < 128; ++k) o = fmaf(sz2[k], dW3[k * 7 + tid], o);
    out[b * 7 + tid] = o;
  }
}

// ---------------------------------------------------------------------------
extern "C" void kernel_launch(void* const* d_in, const int* in_sizes, int n_in,
                              void* d_out, int out_size, void* d_ws, size_t ws_size,
                              hipStream_t stream) {
  const float* bf   = (const float*)d_in[0];
  const float* emb  = (const float*)d_in[1];
  const float* mask = (const float*)d_in[2];
  const float* eW1 = (const float*)d_in[3];
  const float* eb1 = (const float*)d_in[4];
  const float* eg1 = (const float*)d_in[5];
  const float* eB1 = (const float*)d_in[6];
  const float* eW2 = (const float*)d_in[7];
  const float* eb2 = (const float*)d_in[8];
  const float* eg2 = (const float*)d_in[9];
  const float* eB2 = (const float*)d_in[10];
  const float* Wq = (const float*)d_in[11];
  const float* bq = (const float*)d_in[12];
  const float* Wk = (const float*)d_in[13];
  const float* bk = (const float*)d_in[14];
  const float* Wv = (const float*)d_in[15];
  const float* bv = (const float*)d_in[16];
  const float* We1 = (const float*)d_in[17];
  const float* be1 = (const float*)d_in[18];
  const float* We2 = (const float*)d_in[19];
  const float* be2 = (const float*)d_in[20];
  const float* Wo = (const float*)d_in[21];
  const float* bo = (const float*)d_in[22];
  const float* og = (const float*)d_in[23];
  const float* oB = (const float*)d_in[24];
  const float* dW1 = (const float*)d_in[25];
  const float* db1 = (const float*)d_in[26];
  const float* dg1 = (const float*)d_in[27];
  const float* dB1 = (const float*)d_in[28];
  const float* dW2 = (const float*)d_in[29];
  const float* db2 = (const float*)d_in[30];
  const float* dg2 = (const float*)d_in[31];
  const float* dB2 = (const float*)d_in[32];
  const float* dW3 = (const float*)d_in[33];
  const float* db3 = (const float*)d_in[34];
  float* out = (float*)d_out;

  float* ws = (float*)d_ws;
  float* bcat = ws;                          // 1152 f32
  __bf16* w1pk   = (__bf16*)(ws + 1280);     // 8192 bf16
  __bf16* w2pk   = w1pk + 8192;              // 16384
  __bf16* wcatpk = w2pk + 16384;             // 3*49152
  __bf16* wopk   = wcatpk + 3 * 49152;       // 3*16384

  prep_kernel<<<57, 256, 0, stream>>>(Wq, bq, Wk, bk, bv, We1, be1,
                                      eW1, eW2, Wv, Wo, w1pk, w2pk, wcatpk, wopk, bcat);
  mega_kernel<<<128, 512, 0, stream>>>(
      emb, mask, bf, eb1, eg1, eB1, eb2, eg2, eB2,
      w1pk, w2pk, wcatpk, bcat, We2, be2, wopk, bo, og, oB,
      dW1, db1, dg1, dB1, dW2, db2, dg2, dB2, dW3, db3, out);
}